// Round 16
// baseline (83.100 us; speedup 1.0000x reference)
//
#include <hip/hip_runtime.h>

#define NB 16        // molecules
#define NA 2048      // atoms per molecule
#define BLOCK 256
#define JL 4         // j lane-groups per block
#define JT 8         // j atoms per thread
#define JB (JL*JT)   // 32 j atoms per block
#define SPLIT 64     // i-interleave slots (= BLOCK/JL)
#define RSTRIDE JB   // 32: epilogue read t-consecutive -> conflict-free

__global__ void zero_pot_kernel(float* out) {
    if (threadIdx.x < NB) out[threadIdx.x] = 0.0f;
}

__global__ __launch_bounds__(BLOCK) void coulomb_kernel(
    const float* __restrict__ pos,   // [NB*NA, 3]
    const float* __restrict__ q,     // [NB*NA, 1]
    float* __restrict__ out)         // [NB + NB*NA]
{
    __shared__ float4 sp4[NA];              // 32 KB {x,y,z,q}
    __shared__ float red[SPLIT * RSTRIDE];  // 8 KB  -> total 40 KB = 4 blocks/CU

    const int t = threadIdx.x;
    const int blocksPerMol = NA / JB;            // 64
    const int mol   = blockIdx.x / blocksPerMol;
    const int jBase = (blockIdx.x % blocksPerMol) * JB;
    const long molAtom = (long)mol * NA;

    for (int k = t; k < NA; k += BLOCK) {
        const long a = molAtom + k;
        sp4[k] = make_float4(pos[a*3+0], pos[a*3+1], pos[a*3+2], q[a]);
    }
    __syncthreads();

    const int jl  = t & (JL - 1);    // 0..3
    const int sid = t >> 2;          // 0..63: i-interleave slot

    float4 jp[JT];
    int    jidx[JT];
    #pragma unroll
    for (int m = 0; m < JT; ++m) {
        jidx[m] = jBase + jl + m * JL;
        jp[m]   = sp4[jidx[m]];
    }

    float acc[JT];
    #pragma unroll
    for (int m = 0; m < JT; ++m) acc[m] = 0.0f;

    // Prefetch pipeline: p holds iteration k's atom, pn loads k+1 under compute.
    float4 p = sp4[sid];
    #pragma unroll 4
    for (int k = 0; k < NA / SPLIT; ++k) {
        const int inext = ((k + 1) * SPLIT + sid) & (NA - 1);  // branchless wrap
        const float4 pn = sp4[inext];
        const int i = k * SPLIT + sid;
        #pragma unroll
        for (int m = 0; m < JT; ++m) {
            float dx = p.x - jp[m].x;
            float dy = p.y - jp[m].y;
            float dz = p.z - jp[m].z;
            float d2 = fmaf(dx, dx, fmaf(dy, dy, fmaf(dz, dz, 1e-16f)));
            float inv = __builtin_amdgcn_rsqf(d2);   // d2 >= 1e-16: finite
            float qs  = (i == jidx[m]) ? 0.0f : p.w; // diagonal mask
            acc[m] = fmaf(qs, inv, acc[m]);
        }
        p = pn;
    }

    #pragma unroll
    for (int m = 0; m < JT; ++m)
        red[sid * RSTRIDE + jl + m * JL] = acc[m];
    __syncthreads();

    if (t < JB) {
        float field = 0.0f;
        #pragma unroll
        for (int s = 0; s < SPLIT; ++s) field += red[s * RSTRIDE + t];

        out[NB + molAtom + jBase + t] = field;          // q_field

        float pot = 0.5f * sp4[jBase + t].w * field;    // potential partial
        #pragma unroll
        for (int off = 16; off > 0; off >>= 1)
            pot += __shfl_down(pot, off, 32);
        if (t == 0) atomicAdd(&out[mol], pot);
    }
}

extern "C" void kernel_launch(void* const* d_in, const int* in_sizes, int n_in,
                              void* d_out, int out_size, void* d_ws, size_t ws_size,
                              hipStream_t stream) {
    const float* pos = (const float*)d_in[0];
    const float* q   = (const float*)d_in[1];
    float* out = (float*)d_out;

    zero_pot_kernel<<<1, 64, 0, stream>>>(out);

    const int grid = NB * (NA / JB);   // 1024 blocks -> 4 blocks/CU
    coulomb_kernel<<<grid, BLOCK, 0, stream>>>(pos, q, out);
}